// Round 27
// baseline (233.502 us; speedup 1.0000x reference)
//
#include <hip/hip_runtime.h>
#include <hip/hip_fp16.h>
#include <math.h>

#define HH 128
#define WW 128
#define PLANE (HH*WW)
#define BB 4

typedef _Float16 f16x8 __attribute__((ext_vector_type(8)));
typedef _Float16 f16x4 __attribute__((ext_vector_type(4)));
typedef float f32x4 __attribute__((ext_vector_type(4)));

__device__ __forceinline__ float lrelu(float v) { return v >= 0.f ? v : 0.1f * v; }

__device__ __forceinline__ uint32_t pack2h(float a, float b) {
    return (uint32_t)__half_as_ushort(__float2half(b)) << 16 |
           (uint32_t)__half_as_ushort(__float2half(a));
}

// ---------------------------------------------------------------------------
// Single fused prologue: all weight repacks AND both NCHW->grouped-G converts
// in ONE dispatch (blockIdx ranges). grid = 2016 + 512 = 2528 blocks.
// ---------------------------------------------------------------------------
__device__ __forceinline__ void repack_w16_body(const float* __restrict__ src,
                                                __half* __restrict__ dst,
                                                int Cout, int Cin, int OPAD, int idx)
{
    int total = Cin * 9 * OPAD;
    if (idx >= total) return;
    int cp   = idx & 31;
    int o    = (idx >> 5) % OPAD;
    int rest = idx / (32 * OPAD);
    int tap  = rest % 9;
    int cc   = rest / 9;
    int c = cc * 32 + cp;
    float v = (o < Cout) ? src[((size_t)o * Cin + c) * 9 + tap] : 0.f;
    dst[idx] = __float2half(v);
}

__device__ __forceinline__ void repack_dcn_body(const float* __restrict__ w,
                                                __half* __restrict__ wr, int idx)
{
    if (idx >= 18 * 64 * 32) return;
    int k  = idx & 31;
    int o  = (idx >> 5) & 63;
    int cc = idx >> 11;
    int tl = k >> 3, c = k & 7;
    int gk = cc * 4 + tl;
    int g = gk / 9, k2 = gk - g * 9;
    wr[idx] = __float2half(w[((size_t)o * 64 + g * 8 + c) * 9 + k2]);
}

__global__ __launch_bounds__(256)
void prologue_kernel(const float* __restrict__ fea, const float* __restrict__ ref,
                     __half* __restrict__ G0, __half* __restrict__ G1,
                     const float* w_of1, const float* w_or1, const float* w_of2,
                     const float* w_or2, const float* w_om,  const float* w_fu1,
                     const float* w_fu2, const float* w_dcn,
                     __half* W0, __half* W1, __half* W2, __half* W3,
                     __half* W4, __half* W5, __half* W6, __half* W7h)
{
    const int bx = blockIdx.x;
    const int t  = threadIdx.x;
    if      (bx <  288) { repack_w16_body(w_of1, W0,  64, 128,  64, (bx       ) * 256 + t); return; }
    else if (bx <  576) { repack_w16_body(w_or1, W1,  64, 128,  64, (bx -  288) * 256 + t); return; }
    else if (bx <  720) { repack_w16_body(w_of2, W2,  64,  64,  64, (bx -  576) * 256 + t); return; }
    else if (bx <  864) { repack_w16_body(w_or2, W3,  64,  64,  64, (bx -  720) * 256 + t); return; }
    else if (bx < 1440) { repack_w16_body(w_om,  W4, 216,  64, 256, (bx -  864) * 256 + t); return; }
    else if (bx < 1728) { repack_w16_body(w_fu1, W5,  64, 128,  64, (bx - 1440) * 256 + t); return; }
    else if (bx < 1872) { repack_w16_body(w_fu2, W6,  64,  64,  64, (bx - 1728) * 256 + t); return; }
    else if (bx < 2016) { repack_dcn_body(w_dcn, W7h,               (bx - 1872) * 256 + t); return; }

    const int bx2 = bx - 2016;
    const int j = bx2 >> 8;
    const float* in = j ? ref : fea;
    __half* out     = j ? G1 : G0;
    int pix = (bx2 & 255) * 256 + t;
    int b = pix >> 14;
    int p = pix & 16383;
    const float* src = in + (size_t)b * 64 * PLANE + p;
    uint32_t buf[32];
#pragma unroll
    for (int c = 0; c < 64; c += 2)
        buf[c >> 1] = pack2h(src[(size_t)c * PLANE], src[(size_t)(c + 1) * PLANE]);
#pragma unroll
    for (int g = 0; g < 8; ++g) {
        uint4* dst = (uint4*)(out + ((size_t)(b * 8 + g) * PLANE + p) * 8);
        *dst = make_uint4(buf[4*g], buf[4*g+1], buf[4*g+2], buf[4*g+3]);
    }
}

// ---------------------------------------------------------------------------
// MFMA implicit-GEMM 3x3 conv — T14 async-STAGE split + T5 setprio.
// Tap loop FULLY unrolled (was unroll 3): compiler can software-pipeline all
// 36 af global loads + 36 bf LDS reads across the kg's 144-MFMA stream.
// VGPR headroom is safe: LDS (51.8KB x 3) is the occupancy limiter, not VGPR.
// OM padding trim: OUTMODE==1 last chunk computes only mt<2 (ch 192-223).
// ---------------------------------------------------------------------------
template<int KG, int CHUNKS, int OUTMODE, bool GIN, bool SWZ>
__global__ __launch_bounds__(256, 3)
void conv_mfma_kernel(const __half* __restrict__ x0a, const __half* __restrict__ x1a,
                      const __half* __restrict__ x0b, const __half* __restrict__ x1b,
                      const __half* __restrict__ wa,  const __half* __restrict__ wb,
                      const float* __restrict__ ba,   const float* __restrict__ bb,
                      void* __restrict__ outa, void* __restrict__ outb,
                      int CoutReal)
{
    constexpr int OPAD = CHUNKS * 64;
    const int tid  = threadIdx.x;
    const int lane = tid & 63;
    const int wv   = tid >> 6;
    const int p16  = lane & 15;
    const int q    = lane >> 4;

    int job, b, chunk, tx0, ty0;
    if (SWZ) {
        job = blockIdx.x >> 2;  b = blockIdx.x & 3;
        chunk = (CHUNKS > 1) ? (blockIdx.z >> 3) : 0;
        ty0 = ((CHUNKS > 1) ? (blockIdx.z & 7) : blockIdx.z) * 16;
        tx0 = blockIdx.y * 16;
    } else {
        const int zz = blockIdx.z;
        job = zz / (BB * CHUNKS);
        const int rem = zz % (BB * CHUNKS);
        chunk = rem / BB;  b = rem % BB;
        tx0 = blockIdx.x * 16;  ty0 = blockIdx.y * 16;
    }
    const int oc0 = chunk * 64;
    // om padding trim: last chunk only needs 32 output channels (192..223)
    const int mtmax = (OUTMODE == 1 && chunk == CHUNKS - 1) ? 2 : 4;

    const __half* x0  = job ? x0b : x0a;
    const __half* x1  = job ? x1b : x1a;
    const __half* wr  = job ? wb  : wa;
    const float* bias = job ? bb  : ba;
    void* outp        = job ? outb : outa;

    __shared__ __align__(16) __half act[2][18 * 18 * 40];   // 51840 B -> 3 blk/CU

    uint4 pf[6];

    auto stage_load = [&](int kg) {
        const __half* src = (KG == 4 && kg >= 2) ? x1 : x0;
        const int csel = (KG == 4) ? (kg & 1) : kg;
#pragma unroll
        for (int i = 0; i < 6; ++i) {
            int t = tid + i * 256;
            uint4 v = make_uint4(0, 0, 0, 0);
            if (t < 1296) {
                int pix = t >> 2, qq = t & 3;
                int ry = pix / 18, cx = pix - ry * 18;
                int y = ty0 + ry - 1, x = tx0 + cx - 1;
                if ((unsigned)y < HH && (unsigned)x < WW) {
                    if (GIN)
                        v = *(const uint4*)(src + ((size_t)(b * 8 + csel * 4 + qq) * PLANE
                                            + (y * WW + x)) * 8);
                    else
                        v = *(const uint4*)(src + ((size_t)((b * HH + y) * WW + x)) * 64
                                            + csel * 32 + qq * 8);
                }
            }
            pf[i] = v;
        }
    };
    auto stage_write = [&](int buf) {
#pragma unroll
        for (int i = 0; i < 6; ++i) {
            int t = tid + i * 256;
            if (t < 1296) {
                int pix = t >> 2, qq = t & 3;
                *(uint4*)(&act[buf][pix * 40 + qq * 8]) = pf[i];
            }
        }
    };

    f32x4 acc[4][4];
#pragma unroll
    for (int mt = 0; mt < 4; ++mt)
#pragma unroll
        for (int nt = 0; nt < 4; ++nt)
            acc[mt][nt] = (f32x4)(0.f);

    stage_load(0);
    stage_write(0);
    __syncthreads();

#pragma unroll 1
    for (int kg = 0; kg < KG; ++kg) {
        if (kg + 1 < KG) stage_load(kg + 1);   // issue early: hides under taps

#pragma unroll
        for (int tap = 0; tap < 9; ++tap) {
            const int step = kg * 9 + tap;
            f16x8 af[4];
#pragma unroll
            for (int mt = 0; mt < 4; ++mt)
                if (mt < mtmax)
                    af[mt] = *(const f16x8*)(wr
                        + ((size_t)(step * OPAD + oc0 + mt * 16 + p16)) * 32 + q * 8);
            const int dy = tap / 3, dx = tap % 3;
            __builtin_amdgcn_s_setprio(1);     // T5: favor MFMA-phase waves
#pragma unroll
            for (int nt = 0; nt < 4; ++nt) {
                int ry = 4 * wv + nt + dy;
                int cx = p16 + dx;
                f16x8 bf = *(const f16x8*)(&act[kg & 1][(ry * 18 + cx) * 40 + q * 8]);
#pragma unroll
                for (int mt = 0; mt < 4; ++mt)
                    if (mt < mtmax)
                        acc[mt][nt] = __builtin_amdgcn_mfma_f32_16x16x32_f16(
                            af[mt], bf, acc[mt][nt], 0, 0, 0);
            }
            __builtin_amdgcn_s_setprio(0);
        }

        if (kg + 1 < KG) {
            stage_write((kg + 1) & 1);   // write prefetched regs to other buffer
            __syncthreads();             // make visible before next kg's reads
        }
    }

    float bv[4][4];
#pragma unroll
    for (int mt = 0; mt < 4; ++mt)
#pragma unroll
        for (int r = 0; r < 4; ++r) {
            int o = oc0 + mt * 16 + q * 4 + r;
            bv[mt][r] = (o < CoutReal) ? bias[o] : 0.f;
        }

    const int xg = tx0 + p16;
#pragma unroll
    for (int nt = 0; nt < 4; ++nt) {
        int yg = ty0 + 4 * wv + nt;
        if (OUTMODE == 0) {
            __half* op = (__half*)outp + ((size_t)((b * HH + yg) * WW + xg)) * 64;
#pragma unroll
            for (int mt = 0; mt < 4; ++mt) {
                float v0 = lrelu(acc[mt][nt][0] + bv[mt][0]);
                float v1 = lrelu(acc[mt][nt][1] + bv[mt][1]);
                float v2 = lrelu(acc[mt][nt][2] + bv[mt][2]);
                float v3 = lrelu(acc[mt][nt][3] + bv[mt][3]);
                *(uint2*)(op + mt * 16 + q * 4) = make_uint2(pack2h(v0, v1), pack2h(v2, v3));
            }
        } else if (OUTMODE == 1) {
            __half* op = (__half*)outp
                       + ((size_t)(chunk * BB + b) * PLANE + yg * WW + xg) * 64;
#pragma unroll
            for (int mt = 0; mt < 4; ++mt) {
                int o = oc0 + mt * 16 + q * 4;
                if (mt < mtmax && o + 3 < 216) {
                    float v0 = acc[mt][nt][0] + bv[mt][0];
                    float v1 = acc[mt][nt][1] + bv[mt][1];
                    float v2 = acc[mt][nt][2] + bv[mt][2];
                    float v3 = acc[mt][nt][3] + bv[mt][3];
                    *(uint2*)(op + mt * 16 + q * 4) = make_uint2(pack2h(v0, v1), pack2h(v2, v3));
                }
            }
        } else {
            float* op = (float*)outp + ((size_t)(b * 64) * HH) * WW + yg * WW + xg;
#pragma unroll
            for (int mt = 0; mt < 4; ++mt)
#pragma unroll
                for (int r = 0; r < 4; ++r) {
                    int o = mt * 16 + q * 4 + r;
                    op[(size_t)o * PLANE] = lrelu(acc[mt][nt][r] + bv[mt][r]);
                }
        }
    }
}

// ---------------------------------------------------------------------------
// DCN v2 MFMA implicit-GEMM — 4-way K-split, 16x8 px tiles, barrier-free
// main loop, T5 setprio around the MFMA cluster (round-23 win: 91.5->77 us).
// UNCHANGED: VGPR=64 is exactly the 4-blocks/CU occupancy boundary.
// ---------------------------------------------------------------------------
__global__ __launch_bounds__(512, 4)
void dcn_mfma_kernel(const __half* __restrict__ ga, const __half* __restrict__ gb,
                     const __half* __restrict__ oma, const __half* __restrict__ omb,
                     const __half* __restrict__ wr, const float* __restrict__ bias,
                     __half* __restrict__ outa, __half* __restrict__ outb)
{
    const int tid  = threadIdx.x;
    const int qtr  = tid >> 7;
    const int t7   = tid & 127;
    const int lane = tid & 63;
    const int wv2  = (tid >> 6) & 1;
    const int p16  = lane & 15;
    const int q    = lane >> 4;
    const int job  = blockIdx.x >> 2;
    const int b    = blockIdx.x & 3;
    const int tx0  = blockIdx.y * 16;
    const int ty0  = blockIdx.z * 8;

    const __half* G  = job ? gb : ga;
    const __half* om = job ? omb : oma;
    __half* out      = job ? outb : outa;

    const int xs = tx0 + (t7 & 15);
    const int ys = ty0 + (t7 >> 4);
    const int pxl = ys * WW + xs;

    __shared__ __align__(16) __half colbuf[4][128 * 40];

    f32x4 acc[4][4];
#pragma unroll
    for (int mt = 0; mt < 4; ++mt)
#pragma unroll
        for (int nt = 0; nt < 4; ++nt)
            acc[mt][nt] = (f32x4)(0.f);

    const int cc0 = (qtr * 18) >> 2;
    const int cc1 = ((qtr + 1) * 18) >> 2;

#pragma unroll 2
    for (int cc = cc0; cc < cc1; ++cc) {
        const int ch_d = 8 * cc;
        const int ch_m = 144 + 4 * cc;
        f16x8 ddv = *(const f16x8*)(om + ((size_t)((ch_d >> 6) * BB + b) * PLANE + pxl) * 64
                                    + (ch_d & 63));
        f16x4 mkv = *(const f16x4*)(om + ((size_t)((ch_m >> 6) * BB + b) * PLANE + pxl) * 64
                                    + (ch_m & 63));

        f16x8 af[4];
#pragma unroll
        for (int mt = 0; mt < 4; ++mt)
            af[mt] = *(const f16x8*)(wr + ((size_t)(cc * 64 + mt * 16 + p16)) * 32 + q * 8);

#pragma unroll
        for (int tl = 0; tl < 4; ++tl) {
            int gk = cc * 4 + tl;
            int g  = gk / 9;
            int k2 = gk - g * 9;
            int kyi = k2 / 3, kxi = k2 - kyi * 3;

            float dyo = (float)ddv[2 * tl];
            float dxo = (float)ddv[2 * tl + 1];
            float mk  = 1.f / (1.f + __expf(-(float)mkv[tl]));

            float py = (float)(ys + kyi - 1) + dyo;
            float px = (float)(xs + kxi - 1) + dxo;
            float fy = floorf(py), fx = floorf(px);
            int   y0 = (int)fy,    x0 = (int)fx;
            float ly = py - fy,    lx = px - fx;
            int   y1 = y0 + 1,     x1 = x0 + 1;

            float vy0 = (y0 >= 0 && y0 < HH) ? 1.f : 0.f;
            float vy1 = (y1 >= 0 && y1 < HH) ? 1.f : 0.f;
            float vx0 = (x0 >= 0 && x0 < WW) ? 1.f : 0.f;
            float vx1 = (x1 >= 0 && x1 < WW) ? 1.f : 0.f;

            _Float16 w00 = (_Float16)((1.f - ly) * (1.f - lx) * vy0 * vx0 * mk);
            _Float16 w01 = (_Float16)((1.f - ly) * lx         * vy0 * vx1 * mk);
            _Float16 w10 = (_Float16)(ly         * (1.f - lx) * vy1 * vx0 * mk);
            _Float16 w11 = (_Float16)(ly         * lx         * vy1 * vx1 * mk);

            int cy0 = min(max(y0, 0), HH - 1);
            int cy1 = min(max(y1, 0), HH - 1);
            int cx0 = min(max(x0, 0), WW - 1);
            int cx1 = min(max(x1, 0), WW - 1);
            const __half* gp = G + (size_t)(b * 8 + g) * PLANE * 8;
            f16x8 c00 = *(const f16x8*)(gp + (size_t)(cy0 * WW + cx0) * 8);
            f16x8 c01 = *(const f16x8*)(gp + (size_t)(cy0 * WW + cx1) * 8);
            f16x8 c10 = *(const f16x8*)(gp + (size_t)(cy1 * WW + cx0) * 8);
            f16x8 c11 = *(const f16x8*)(gp + (size_t)(cy1 * WW + cx1) * 8);

            f16x8 pv = c00 * w00 + c01 * w01 + c10 * w10 + c11 * w11;
            *(f16x8*)(&colbuf[qtr][t7 * 40 + tl * 8]) = pv;
        }

        __builtin_amdgcn_s_setprio(1);     // T5: favor MFMA-phase waves
#pragma unroll
        for (int nt = 0; nt < 4; ++nt) {
            f16x8 bf = *(const f16x8*)(&colbuf[qtr][(wv2 * 64 + nt * 16 + p16) * 40 + q * 8]);
#pragma unroll
            for (int mt = 0; mt < 4; ++mt)
                acc[mt][nt] = __builtin_amdgcn_mfma_f32_16x16x32_f16(
                    af[mt], bf, acc[mt][nt], 0, 0, 0);
        }
        __builtin_amdgcn_s_setprio(0);
    }

    __syncthreads();

    float* red = (float*)&colbuf[0][0];
#pragma unroll
    for (int mt = 0; mt < 4; ++mt) {
        if (qtr != 0) {
#pragma unroll
            for (int nt = 0; nt < 4; ++nt) {
                int pxi = wv2 * 64 + nt * 16 + p16;
                *(f32x4*)(&red[((qtr - 1) * 128 + pxi) * 17 + q * 4]) = acc[mt][nt];
            }
        }
        __syncthreads();
        if (qtr == 0) {
#pragma unroll
            for (int nt = 0; nt < 4; ++nt) {
                int pxi = wv2 * 64 + nt * 16 + p16;
                acc[mt][nt] += *(const f32x4*)(&red[(pxi) * 17 + q * 4]);
                acc[mt][nt] += *(const f32x4*)(&red[(128 + pxi) * 17 + q * 4]);
                acc[mt][nt] += *(const f32x4*)(&red[(256 + pxi) * 17 + q * 4]);
            }
        }
        __syncthreads();
    }

    if (qtr == 0) {
        const int xg = tx0 + p16;
#pragma unroll
        for (int nt = 0; nt < 4; ++nt) {
            int yg = ty0 + 4 * wv2 + nt;
            __half* op = out + ((size_t)((b * HH + yg) * WW + xg)) * 64;
#pragma unroll
            for (int mt = 0; mt < 4; ++mt) {
                int o = mt * 16 + q * 4;
                float v0 = lrelu(acc[mt][nt][0] + bias[o]);
                float v1 = lrelu(acc[mt][nt][1] + bias[o + 1]);
                float v2 = lrelu(acc[mt][nt][2] + bias[o + 2]);
                float v3 = lrelu(acc[mt][nt][3] + bias[o + 3]);
                *(uint2*)(op + o) = make_uint2(pack2h(v0, v1), pack2h(v2, v3));
            }
        }
    }
}

// ---------------------------------------------------------------------------
extern "C" void kernel_launch(void* const* d_in, const int* in_sizes, int n_in,
                              void* d_out, int out_size, void* d_ws, size_t ws_size,
                              hipStream_t stream) {
    const float* fea   = (const float*)d_in[0];
    const float* ref   = (const float*)d_in[1];
    const float* w_of1 = (const float*)d_in[2];
    const float* b_of1 = (const float*)d_in[3];
    const float* w_of2 = (const float*)d_in[4];
    const float* b_of2 = (const float*)d_in[5];
    const float* w_or1 = (const float*)d_in[6];
    const float* b_or1 = (const float*)d_in[7];
    const float* w_or2 = (const float*)d_in[8];
    const float* b_or2 = (const float*)d_in[9];
    const float* w_om  = (const float*)d_in[10];
    const float* b_om  = (const float*)d_in[11];
    const float* w_dcn = (const float*)d_in[12];
    const float* b_dcn = (const float*)d_in[13];
    const float* w_fu1 = (const float*)d_in[14];
    const float* b_fu1 = (const float*)d_in[15];
    const float* w_fu2 = (const float*)d_in[16];
    const float* b_fu2 = (const float*)d_in[17];

    char* ws = (char*)d_ws;
    constexpr size_t SLOT = (size_t)BB * PLANE * 64 * 2;     //  8,388,608
    constexpr size_t OMSZ = 4 * SLOT;                        // 33,554,432 (4 planes)
    // weights header [0, 1 MB)
    __half* W0  = (__half*)(ws);
    __half* W1  = (__half*)(ws + 147456);
    __half* W2  = (__half*)(ws + 294912);
    __half* W3  = (__half*)(ws + 368640);
    __half* W4  = (__half*)(ws + 442368);
    __half* W5  = (__half*)(ws + 737280);
    __half* W6  = (__half*)(ws + 884736);
    __half* W7h = (__half*)(ws + 958464);
    // activation slots; ws high-water ~101.7 MB
    __half* G0  = (__half*)(ws + 1048576);
    __half* G1  = (__half*)(ws + 1048576 + SLOT);
    __half* Y   = (__half*)(ws + 1048576 + 2 * SLOT);
    __half* Z   = (__half*)(ws + 1048576 + 3 * SLOT);
    char*  OMa_ = ws + 1048576 + 4 * SLOT;
    char*  OMb_ = OMa_ + OMSZ;
    __half* OMa = (__half*)OMa_;
    __half* OMb = (__half*)OMb_;
    __half* X2  = (__half*)OMa_;              // of1 out a (dies before om)
    __half* X3  = (__half*)(OMa_ + SLOT);     // of1 out b
    __half* D0  = Y;                          // dcn out a (Y dead)
    __half* D1  = Z;                          // dcn out b (Z dead)
    __half* F   = G0;                         // fuse1 out (G0 dead)

    dim3 blk256(256, 1, 1);

    // single fused prologue: repacks + converts in one dispatch
    prologue_kernel<<<2528, blk256, 0, stream>>>(
        fea, ref, G0, G1,
        w_of1, w_or1, w_of2, w_or2, w_om, w_fu1, w_fu2, w_dcn,
        W0, W1, W2, W3, W4, W5, W6, W7h);

    // of1 pair (G-layout in, SWZ): [G0||G1] -> X2 ; [G1||G0] -> X3
    conv_mfma_kernel<4, 1, 0, true, true><<<dim3(8, 8, 8), blk256, 0, stream>>>(
        G0, G1, G1, G0, W0, W1, b_of1, b_or1, X2, X3, 64);
    // of2 pair (one dispatch): X2 -> Y ; X3 -> Z
    conv_mfma_kernel<2, 1, 0, false, false><<<dim3(8, 8, 8), blk256, 0, stream>>>(
        X2, X2, X3, X3, W2, W3, b_of2, b_or2, Y, Z, 64);
    // om pair (SWZ, 4-plane out, chunk-3 MT trim): Y -> OMa ; Z -> OMb
    conv_mfma_kernel<2, 4, 1, false, true><<<dim3(8, 8, 32), blk256, 0, stream>>>(
        Y, Y, Z, Z, W4, W4, b_om, b_om, OMa, OMb, 216);
    // dcn pair (4-way K-split, 16x8 tiles, T5): (G0,OMa)->D0 ; (G1,OMb)->D1
    dcn_mfma_kernel<<<dim3(8, 8, 16), dim3(512, 1, 1), 0, stream>>>(
        G0, G1, OMa, OMb, W7h, b_dcn, D0, D1);
    // fuse1: [D0||D1] -> F
    conv_mfma_kernel<4, 1, 0, false, false><<<dim3(8, 8, 4), blk256, 0, stream>>>(
        D0, D1, D0, D1, W5, W5, b_fu1, b_fu1, F, F, 64);
    // fuse2: F -> d_out (NCHW fp32 + lrelu)
    conv_mfma_kernel<2, 1, 2, false, false><<<dim3(8, 8, 4), blk256, 0, stream>>>(
        F, F, F, F, W6, W6, b_fu2, b_fu2, d_out, d_out, 64);

    (void)in_sizes; (void)n_in; (void)out_size; (void)ws_size;
}

// Round 28
// 232.050 us; speedup vs baseline: 1.0063x; 1.0063x over previous
//
#include <hip/hip_runtime.h>
#include <hip/hip_fp16.h>
#include <math.h>

#define HH 128
#define WW 128
#define PLANE (HH*WW)
#define BB 4

typedef _Float16 f16x8 __attribute__((ext_vector_type(8)));
typedef _Float16 f16x4 __attribute__((ext_vector_type(4)));
typedef float f32x4 __attribute__((ext_vector_type(4)));

__device__ __forceinline__ float lrelu(float v) { return v >= 0.f ? v : 0.1f * v; }

__device__ __forceinline__ uint32_t pack2h(float a, float b) {
    return (uint32_t)__half_as_ushort(__float2half(b)) << 16 |
           (uint32_t)__half_as_ushort(__float2half(a));
}

// ---------------------------------------------------------------------------
// Single fused prologue: all weight repacks AND both NCHW->grouped-G converts
// in ONE dispatch (blockIdx ranges). grid = 2016 + 512 = 2528 blocks.
// ---------------------------------------------------------------------------
__device__ __forceinline__ void repack_w16_body(const float* __restrict__ src,
                                                __half* __restrict__ dst,
                                                int Cout, int Cin, int OPAD, int idx)
{
    int total = Cin * 9 * OPAD;
    if (idx >= total) return;
    int cp   = idx & 31;
    int o    = (idx >> 5) % OPAD;
    int rest = idx / (32 * OPAD);
    int tap  = rest % 9;
    int cc   = rest / 9;
    int c = cc * 32 + cp;
    float v = (o < Cout) ? src[((size_t)o * Cin + c) * 9 + tap] : 0.f;
    dst[idx] = __float2half(v);
}

__device__ __forceinline__ void repack_dcn_body(const float* __restrict__ w,
                                                __half* __restrict__ wr, int idx)
{
    if (idx >= 18 * 64 * 32) return;
    int k  = idx & 31;
    int o  = (idx >> 5) & 63;
    int cc = idx >> 11;
    int tl = k >> 3, c = k & 7;
    int gk = cc * 4 + tl;
    int g = gk / 9, k2 = gk - g * 9;
    wr[idx] = __float2half(w[((size_t)o * 64 + g * 8 + c) * 9 + k2]);
}

__global__ __launch_bounds__(256)
void prologue_kernel(const float* __restrict__ fea, const float* __restrict__ ref,
                     __half* __restrict__ G0, __half* __restrict__ G1,
                     const float* w_of1, const float* w_or1, const float* w_of2,
                     const float* w_or2, const float* w_om,  const float* w_fu1,
                     const float* w_fu2, const float* w_dcn,
                     __half* W0, __half* W1, __half* W2, __half* W3,
                     __half* W4, __half* W5, __half* W6, __half* W7h)
{
    const int bx = blockIdx.x;
    const int t  = threadIdx.x;
    if      (bx <  288) { repack_w16_body(w_of1, W0,  64, 128,  64, (bx       ) * 256 + t); return; }
    else if (bx <  576) { repack_w16_body(w_or1, W1,  64, 128,  64, (bx -  288) * 256 + t); return; }
    else if (bx <  720) { repack_w16_body(w_of2, W2,  64,  64,  64, (bx -  576) * 256 + t); return; }
    else if (bx <  864) { repack_w16_body(w_or2, W3,  64,  64,  64, (bx -  720) * 256 + t); return; }
    else if (bx < 1440) { repack_w16_body(w_om,  W4, 216,  64, 256, (bx -  864) * 256 + t); return; }
    else if (bx < 1728) { repack_w16_body(w_fu1, W5,  64, 128,  64, (bx - 1440) * 256 + t); return; }
    else if (bx < 1872) { repack_w16_body(w_fu2, W6,  64,  64,  64, (bx - 1728) * 256 + t); return; }
    else if (bx < 2016) { repack_dcn_body(w_dcn, W7h,               (bx - 1872) * 256 + t); return; }

    const int bx2 = bx - 2016;
    const int j = bx2 >> 8;
    const float* in = j ? ref : fea;
    __half* out     = j ? G1 : G0;
    int pix = (bx2 & 255) * 256 + t;
    int b = pix >> 14;
    int p = pix & 16383;
    const float* src = in + (size_t)b * 64 * PLANE + p;
    uint32_t buf[32];
#pragma unroll
    for (int c = 0; c < 64; c += 2)
        buf[c >> 1] = pack2h(src[(size_t)c * PLANE], src[(size_t)(c + 1) * PLANE]);
#pragma unroll
    for (int g = 0; g < 8; ++g) {
        uint4* dst = (uint4*)(out + ((size_t)(b * 8 + g) * PLANE + p) * 8);
        *dst = make_uint4(buf[4*g], buf[4*g+1], buf[4*g+2], buf[4*g+3]);
    }
}

// ---------------------------------------------------------------------------
// MFMA implicit-GEMM 3x3 conv — T14 async-STAGE split + T5 setprio.
// Tap loop unroll 3 (best measured; full unroll regressed in r27).
// OM padding trim: OUTMODE==1 last chunk computes only mt<2 (ch 192-223;
// real channels end at 215) — skips 62%-wasted MFMA/af work in that chunk.
// ---------------------------------------------------------------------------
template<int KG, int CHUNKS, int OUTMODE, bool GIN, bool SWZ>
__global__ __launch_bounds__(256, 3)
void conv_mfma_kernel(const __half* __restrict__ x0a, const __half* __restrict__ x1a,
                      const __half* __restrict__ x0b, const __half* __restrict__ x1b,
                      const __half* __restrict__ wa,  const __half* __restrict__ wb,
                      const float* __restrict__ ba,   const float* __restrict__ bb,
                      void* __restrict__ outa, void* __restrict__ outb,
                      int CoutReal)
{
    constexpr int OPAD = CHUNKS * 64;
    const int tid  = threadIdx.x;
    const int lane = tid & 63;
    const int wv   = tid >> 6;
    const int p16  = lane & 15;
    const int q    = lane >> 4;

    int job, b, chunk, tx0, ty0;
    if (SWZ) {
        job = blockIdx.x >> 2;  b = blockIdx.x & 3;
        chunk = (CHUNKS > 1) ? (blockIdx.z >> 3) : 0;
        ty0 = ((CHUNKS > 1) ? (blockIdx.z & 7) : blockIdx.z) * 16;
        tx0 = blockIdx.y * 16;
    } else {
        const int zz = blockIdx.z;
        job = zz / (BB * CHUNKS);
        const int rem = zz % (BB * CHUNKS);
        chunk = rem / BB;  b = rem % BB;
        tx0 = blockIdx.x * 16;  ty0 = blockIdx.y * 16;
    }
    const int oc0 = chunk * 64;
    // om padding trim: last chunk only needs 32 output channels (192..223)
    const int mtmax = (OUTMODE == 1 && chunk == CHUNKS - 1) ? 2 : 4;

    const __half* x0  = job ? x0b : x0a;
    const __half* x1  = job ? x1b : x1a;
    const __half* wr  = job ? wb  : wa;
    const float* bias = job ? bb  : ba;
    void* outp        = job ? outb : outa;

    __shared__ __align__(16) __half act[2][18 * 18 * 40];   // 51840 B -> 3 blk/CU

    uint4 pf[6];

    auto stage_load = [&](int kg) {
        const __half* src = (KG == 4 && kg >= 2) ? x1 : x0;
        const int csel = (KG == 4) ? (kg & 1) : kg;
#pragma unroll
        for (int i = 0; i < 6; ++i) {
            int t = tid + i * 256;
            uint4 v = make_uint4(0, 0, 0, 0);
            if (t < 1296) {
                int pix = t >> 2, qq = t & 3;
                int ry = pix / 18, cx = pix - ry * 18;
                int y = ty0 + ry - 1, x = tx0 + cx - 1;
                if ((unsigned)y < HH && (unsigned)x < WW) {
                    if (GIN)
                        v = *(const uint4*)(src + ((size_t)(b * 8 + csel * 4 + qq) * PLANE
                                            + (y * WW + x)) * 8);
                    else
                        v = *(const uint4*)(src + ((size_t)((b * HH + y) * WW + x)) * 64
                                            + csel * 32 + qq * 8);
                }
            }
            pf[i] = v;
        }
    };
    auto stage_write = [&](int buf) {
#pragma unroll
        for (int i = 0; i < 6; ++i) {
            int t = tid + i * 256;
            if (t < 1296) {
                int pix = t >> 2, qq = t & 3;
                *(uint4*)(&act[buf][pix * 40 + qq * 8]) = pf[i];
            }
        }
    };

    f32x4 acc[4][4];
#pragma unroll
    for (int mt = 0; mt < 4; ++mt)
#pragma unroll
        for (int nt = 0; nt < 4; ++nt)
            acc[mt][nt] = (f32x4)(0.f);

    stage_load(0);
    stage_write(0);
    __syncthreads();

#pragma unroll 1
    for (int kg = 0; kg < KG; ++kg) {
        if (kg + 1 < KG) stage_load(kg + 1);   // issue early: hides under taps

#pragma unroll 3
        for (int tap = 0; tap < 9; ++tap) {
            const int step = kg * 9 + tap;
            f16x8 af[4];
#pragma unroll
            for (int mt = 0; mt < 4; ++mt)
                if (mt < mtmax)
                    af[mt] = *(const f16x8*)(wr
                        + ((size_t)(step * OPAD + oc0 + mt * 16 + p16)) * 32 + q * 8);
            const int dy = tap / 3, dx = tap % 3;
            __builtin_amdgcn_s_setprio(1);     // T5: favor MFMA-phase waves
#pragma unroll
            for (int nt = 0; nt < 4; ++nt) {
                int ry = 4 * wv + nt + dy;
                int cx = p16 + dx;
                f16x8 bf = *(const f16x8*)(&act[kg & 1][(ry * 18 + cx) * 40 + q * 8]);
#pragma unroll
                for (int mt = 0; mt < 4; ++mt)
                    if (mt < mtmax)
                        acc[mt][nt] = __builtin_amdgcn_mfma_f32_16x16x32_f16(
                            af[mt], bf, acc[mt][nt], 0, 0, 0);
            }
            __builtin_amdgcn_s_setprio(0);
        }

        if (kg + 1 < KG) {
            stage_write((kg + 1) & 1);   // write prefetched regs to other buffer
            __syncthreads();             // make visible before next kg's reads
        }
    }

    float bv[4][4];
#pragma unroll
    for (int mt = 0; mt < 4; ++mt)
#pragma unroll
        for (int r = 0; r < 4; ++r) {
            int o = oc0 + mt * 16 + q * 4 + r;
            bv[mt][r] = (o < CoutReal) ? bias[o] : 0.f;
        }

    const int xg = tx0 + p16;
#pragma unroll
    for (int nt = 0; nt < 4; ++nt) {
        int yg = ty0 + 4 * wv + nt;
        if (OUTMODE == 0) {
            __half* op = (__half*)outp + ((size_t)((b * HH + yg) * WW + xg)) * 64;
#pragma unroll
            for (int mt = 0; mt < 4; ++mt) {
                float v0 = lrelu(acc[mt][nt][0] + bv[mt][0]);
                float v1 = lrelu(acc[mt][nt][1] + bv[mt][1]);
                float v2 = lrelu(acc[mt][nt][2] + bv[mt][2]);
                float v3 = lrelu(acc[mt][nt][3] + bv[mt][3]);
                *(uint2*)(op + mt * 16 + q * 4) = make_uint2(pack2h(v0, v1), pack2h(v2, v3));
            }
        } else if (OUTMODE == 1) {
            __half* op = (__half*)outp
                       + ((size_t)(chunk * BB + b) * PLANE + yg * WW + xg) * 64;
#pragma unroll
            for (int mt = 0; mt < 4; ++mt) {
                int o = oc0 + mt * 16 + q * 4;
                if (mt < mtmax && o + 3 < 216) {
                    float v0 = acc[mt][nt][0] + bv[mt][0];
                    float v1 = acc[mt][nt][1] + bv[mt][1];
                    float v2 = acc[mt][nt][2] + bv[mt][2];
                    float v3 = acc[mt][nt][3] + bv[mt][3];
                    *(uint2*)(op + mt * 16 + q * 4) = make_uint2(pack2h(v0, v1), pack2h(v2, v3));
                }
            }
        } else {
            float* op = (float*)outp + ((size_t)(b * 64) * HH) * WW + yg * WW + xg;
#pragma unroll
            for (int mt = 0; mt < 4; ++mt)
#pragma unroll
                for (int r = 0; r < 4; ++r) {
                    int o = mt * 16 + q * 4 + r;
                    op[(size_t)o * PLANE] = lrelu(acc[mt][nt][r] + bv[mt][r]);
                }
        }
    }
}

// ---------------------------------------------------------------------------
// DCN v2 MFMA implicit-GEMM — 4-way K-split, 16x8 px tiles, barrier-free
// main loop, T5 setprio around the MFMA cluster (round-23 win: 91.5->77 us).
// UNCHANGED: VGPR=64 is exactly the 4-blocks/CU occupancy boundary.
// ---------------------------------------------------------------------------
__global__ __launch_bounds__(512, 4)
void dcn_mfma_kernel(const __half* __restrict__ ga, const __half* __restrict__ gb,
                     const __half* __restrict__ oma, const __half* __restrict__ omb,
                     const __half* __restrict__ wr, const float* __restrict__ bias,
                     __half* __restrict__ outa, __half* __restrict__ outb)
{
    const int tid  = threadIdx.x;
    const int qtr  = tid >> 7;
    const int t7   = tid & 127;
    const int lane = tid & 63;
    const int wv2  = (tid >> 6) & 1;
    const int p16  = lane & 15;
    const int q    = lane >> 4;
    const int job  = blockIdx.x >> 2;
    const int b    = blockIdx.x & 3;
    const int tx0  = blockIdx.y * 16;
    const int ty0  = blockIdx.z * 8;

    const __half* G  = job ? gb : ga;
    const __half* om = job ? omb : oma;
    __half* out      = job ? outb : outa;

    const int xs = tx0 + (t7 & 15);
    const int ys = ty0 + (t7 >> 4);
    const int pxl = ys * WW + xs;

    __shared__ __align__(16) __half colbuf[4][128 * 40];

    f32x4 acc[4][4];
#pragma unroll
    for (int mt = 0; mt < 4; ++mt)
#pragma unroll
        for (int nt = 0; nt < 4; ++nt)
            acc[mt][nt] = (f32x4)(0.f);

    const int cc0 = (qtr * 18) >> 2;
    const int cc1 = ((qtr + 1) * 18) >> 2;

#pragma unroll 2
    for (int cc = cc0; cc < cc1; ++cc) {
        const int ch_d = 8 * cc;
        const int ch_m = 144 + 4 * cc;
        f16x8 ddv = *(const f16x8*)(om + ((size_t)((ch_d >> 6) * BB + b) * PLANE + pxl) * 64
                                    + (ch_d & 63));
        f16x4 mkv = *(const f16x4*)(om + ((size_t)((ch_m >> 6) * BB + b) * PLANE + pxl) * 64
                                    + (ch_m & 63));

        f16x8 af[4];
#pragma unroll
        for (int mt = 0; mt < 4; ++mt)
            af[mt] = *(const f16x8*)(wr + ((size_t)(cc * 64 + mt * 16 + p16)) * 32 + q * 8);

#pragma unroll
        for (int tl = 0; tl < 4; ++tl) {
            int gk = cc * 4 + tl;
            int g  = gk / 9;
            int k2 = gk - g * 9;
            int kyi = k2 / 3, kxi = k2 - kyi * 3;

            float dyo = (float)ddv[2 * tl];
            float dxo = (float)ddv[2 * tl + 1];
            float mk  = 1.f / (1.f + __expf(-(float)mkv[tl]));

            float py = (float)(ys + kyi - 1) + dyo;
            float px = (float)(xs + kxi - 1) + dxo;
            float fy = floorf(py), fx = floorf(px);
            int   y0 = (int)fy,    x0 = (int)fx;
            float ly = py - fy,    lx = px - fx;
            int   y1 = y0 + 1,     x1 = x0 + 1;

            float vy0 = (y0 >= 0 && y0 < HH) ? 1.f : 0.f;
            float vy1 = (y1 >= 0 && y1 < HH) ? 1.f : 0.f;
            float vx0 = (x0 >= 0 && x0 < WW) ? 1.f : 0.f;
            float vx1 = (x1 >= 0 && x1 < WW) ? 1.f : 0.f;

            _Float16 w00 = (_Float16)((1.f - ly) * (1.f - lx) * vy0 * vx0 * mk);
            _Float16 w01 = (_Float16)((1.f - ly) * lx         * vy0 * vx1 * mk);
            _Float16 w10 = (_Float16)(ly         * (1.f - lx) * vy1 * vx0 * mk);
            _Float16 w11 = (_Float16)(ly         * lx         * vy1 * vx1 * mk);

            int cy0 = min(max(y0, 0), HH - 1);
            int cy1 = min(max(y1, 0), HH - 1);
            int cx0 = min(max(x0, 0), WW - 1);
            int cx1 = min(max(x1, 0), WW - 1);
            const __half* gp = G + (size_t)(b * 8 + g) * PLANE * 8;
            f16x8 c00 = *(const f16x8*)(gp + (size_t)(cy0 * WW + cx0) * 8);
            f16x8 c01 = *(const f16x8*)(gp + (size_t)(cy0 * WW + cx1) * 8);
            f16x8 c10 = *(const f16x8*)(gp + (size_t)(cy1 * WW + cx0) * 8);
            f16x8 c11 = *(const f16x8*)(gp + (size_t)(cy1 * WW + cx1) * 8);

            f16x8 pv = c00 * w00 + c01 * w01 + c10 * w10 + c11 * w11;
            *(f16x8*)(&colbuf[qtr][t7 * 40 + tl * 8]) = pv;
        }

        __builtin_amdgcn_s_setprio(1);     // T5: favor MFMA-phase waves
#pragma unroll
        for (int nt = 0; nt < 4; ++nt) {
            f16x8 bf = *(const f16x8*)(&colbuf[qtr][(wv2 * 64 + nt * 16 + p16) * 40 + q * 8]);
#pragma unroll
            for (int mt = 0; mt < 4; ++mt)
                acc[mt][nt] = __builtin_amdgcn_mfma_f32_16x16x32_f16(
                    af[mt], bf, acc[mt][nt], 0, 0, 0);
        }
        __builtin_amdgcn_s_setprio(0);
    }

    __syncthreads();

    float* red = (float*)&colbuf[0][0];
#pragma unroll
    for (int mt = 0; mt < 4; ++mt) {
        if (qtr != 0) {
#pragma unroll
            for (int nt = 0; nt < 4; ++nt) {
                int pxi = wv2 * 64 + nt * 16 + p16;
                *(f32x4*)(&red[((qtr - 1) * 128 + pxi) * 17 + q * 4]) = acc[mt][nt];
            }
        }
        __syncthreads();
        if (qtr == 0) {
#pragma unroll
            for (int nt = 0; nt < 4; ++nt) {
                int pxi = wv2 * 64 + nt * 16 + p16;
                acc[mt][nt] += *(const f32x4*)(&red[(pxi) * 17 + q * 4]);
                acc[mt][nt] += *(const f32x4*)(&red[(128 + pxi) * 17 + q * 4]);
                acc[mt][nt] += *(const f32x4*)(&red[(256 + pxi) * 17 + q * 4]);
            }
        }
        __syncthreads();
    }

    if (qtr == 0) {
        const int xg = tx0 + p16;
#pragma unroll
        for (int nt = 0; nt < 4; ++nt) {
            int yg = ty0 + 4 * wv2 + nt;
            __half* op = out + ((size_t)((b * HH + yg) * WW + xg)) * 64;
#pragma unroll
            for (int mt = 0; mt < 4; ++mt) {
                int o = mt * 16 + q * 4;
                float v0 = lrelu(acc[mt][nt][0] + bias[o]);
                float v1 = lrelu(acc[mt][nt][1] + bias[o + 1]);
                float v2 = lrelu(acc[mt][nt][2] + bias[o + 2]);
                float v3 = lrelu(acc[mt][nt][3] + bias[o + 3]);
                *(uint2*)(op + o) = make_uint2(pack2h(v0, v1), pack2h(v2, v3));
            }
        }
    }
}

// ---------------------------------------------------------------------------
extern "C" void kernel_launch(void* const* d_in, const int* in_sizes, int n_in,
                              void* d_out, int out_size, void* d_ws, size_t ws_size,
                              hipStream_t stream) {
    const float* fea   = (const float*)d_in[0];
    const float* ref   = (const float*)d_in[1];
    const float* w_of1 = (const float*)d_in[2];
    const float* b_of1 = (const float*)d_in[3];
    const float* w_of2 = (const float*)d_in[4];
    const float* b_of2 = (const float*)d_in[5];
    const float* w_or1 = (const float*)d_in[6];
    const float* b_or1 = (const float*)d_in[7];
    const float* w_or2 = (const float*)d_in[8];
    const float* b_or2 = (const float*)d_in[9];
    const float* w_om  = (const float*)d_in[10];
    const float* b_om  = (const float*)d_in[11];
    const float* w_dcn = (const float*)d_in[12];
    const float* b_dcn = (const float*)d_in[13];
    const float* w_fu1 = (const float*)d_in[14];
    const float* b_fu1 = (const float*)d_in[15];
    const float* w_fu2 = (const float*)d_in[16];
    const float* b_fu2 = (const float*)d_in[17];

    char* ws = (char*)d_ws;
    constexpr size_t SLOT = (size_t)BB * PLANE * 64 * 2;     //  8,388,608
    constexpr size_t OMSZ = 4 * SLOT;                        // 33,554,432 (4 planes)
    // weights header [0, 1 MB)
    __half* W0  = (__half*)(ws);
    __half* W1  = (__half*)(ws + 147456);
    __half* W2  = (__half*)(ws + 294912);
    __half* W3  = (__half*)(ws + 368640);
    __half* W4  = (__half*)(ws + 442368);
    __half* W5  = (__half*)(ws + 737280);
    __half* W6  = (__half*)(ws + 884736);
    __half* W7h = (__half*)(ws + 958464);
    // activation slots; ws high-water ~101.7 MB
    __half* G0  = (__half*)(ws + 1048576);
    __half* G1  = (__half*)(ws + 1048576 + SLOT);
    __half* Y   = (__half*)(ws + 1048576 + 2 * SLOT);
    __half* Z   = (__half*)(ws + 1048576 + 3 * SLOT);
    char*  OMa_ = ws + 1048576 + 4 * SLOT;
    char*  OMb_ = OMa_ + OMSZ;
    __half* OMa = (__half*)OMa_;
    __half* OMb = (__half*)OMb_;
    __half* X2  = (__half*)OMa_;              // of1 out a (dies before om)
    __half* X3  = (__half*)(OMa_ + SLOT);     // of1 out b
    __half* D0  = Y;                          // dcn out a (Y dead)
    __half* D1  = Z;                          // dcn out b (Z dead)
    __half* F   = G0;                         // fuse1 out (G0 dead)

    dim3 blk256(256, 1, 1);

    // single fused prologue: repacks + converts in one dispatch
    prologue_kernel<<<2528, blk256, 0, stream>>>(
        fea, ref, G0, G1,
        w_of1, w_or1, w_of2, w_or2, w_om, w_fu1, w_fu2, w_dcn,
        W0, W1, W2, W3, W4, W5, W6, W7h);

    // of1 pair (G-layout in, SWZ): [G0||G1] -> X2 ; [G1||G0] -> X3
    conv_mfma_kernel<4, 1, 0, true, true><<<dim3(8, 8, 8), blk256, 0, stream>>>(
        G0, G1, G1, G0, W0, W1, b_of1, b_or1, X2, X3, 64);
    // of2 pair (one dispatch): X2 -> Y ; X3 -> Z
    conv_mfma_kernel<2, 1, 0, false, false><<<dim3(8, 8, 8), blk256, 0, stream>>>(
        X2, X2, X3, X3, W2, W3, b_of2, b_or2, Y, Z, 64);
    // om pair (SWZ, 4-plane out, chunk-3 MT trim): Y -> OMa ; Z -> OMb
    conv_mfma_kernel<2, 4, 1, false, true><<<dim3(8, 8, 32), blk256, 0, stream>>>(
        Y, Y, Z, Z, W4, W4, b_om, b_om, OMa, OMb, 216);
    // dcn pair (4-way K-split, 16x8 tiles, T5): (G0,OMa)->D0 ; (G1,OMb)->D1
    dcn_mfma_kernel<<<dim3(8, 8, 16), dim3(512, 1, 1), 0, stream>>>(
        G0, G1, OMa, OMb, W7h, b_dcn, D0, D1);
    // fuse1: [D0||D1] -> F
    conv_mfma_kernel<4, 1, 0, false, false><<<dim3(8, 8, 4), blk256, 0, stream>>>(
        D0, D1, D0, D1, W5, W5, b_fu1, b_fu1, F, F, 64);
    // fuse2: F -> d_out (NCHW fp32 + lrelu)
    conv_mfma_kernel<2, 1, 2, false, false><<<dim3(8, 8, 4), blk256, 0, stream>>>(
        F, F, F, F, W6, W6, b_fu2, b_fu2, d_out, d_out, 64);

    (void)in_sizes; (void)n_in; (void)out_size; (void)ws_size;
}